// Round 7
// baseline (129.834 us; speedup 1.0000x reference)
//
#include <hip/hip_runtime.h>

#define T_DIM 2048
#define B_DIM 8192
#define GAMMA 0.99f
#define NCHUNK 256
#define CHUNK_L 8            // rows per chunk (NCHUNK*CHUNK_L == T_DIM)

typedef float v4f __attribute__((ext_vector_type(4)));

__device__ __forceinline__ void nt_store4(float* p, float4 x) {
    __builtin_nontemporal_store(*(v4f*)&x, (v4f*)p);
}

// ---------------------------------------------------------------------------
// Pass 1: read tlp/blp -> rho (NT store, final output), read v/rew -> a,b in
// regs -> chunk composite (A,B) with out[c*L] = A + B*out[(c+1)*L].
// ONLY the small composite arrays are cache-allocating stores; both 64 MiB
// outputs leave via NT so the 256 MiB input set stays L3-resident across
// graph replays.  b[t] = GAMMA*rho[t] except b[T-1] = 0.
// ---------------------------------------------------------------------------
__global__ __launch_bounds__(256) void vtrace_pass1(
    const float* __restrict__ v, const float* __restrict__ rew,
    const float* __restrict__ tlp, const float* __restrict__ blp,
    float* __restrict__ out_rho,    // d_out + T*B (final)
    float* __restrict__ Aw, float* __restrict__ Bw)
{
    const int j    = blockIdx.x * blockDim.x + threadIdx.x;  // 0 .. B/4-1
    const int c    = blockIdx.y;
    const int col  = j * 4;
    const int base = c * CHUNK_L * B_DIM + col;
    const bool last_chunk = (c == NCHUNK - 1);

    // ---- rho from tlp/blp ----
    float4 t4[CHUNK_L], b4[CHUNK_L];
    #pragma unroll
    for (int r = 0; r < CHUNK_L; ++r)
        t4[r] = *(const float4*)(tlp + base + r * B_DIM);
    #pragma unroll
    for (int r = 0; r < CHUNK_L; ++r)
        b4[r] = *(const float4*)(blp + base + r * B_DIM);
    __builtin_amdgcn_sched_barrier(0);

    float4 rho[CHUNK_L];
    #pragma unroll
    for (int r = 0; r < CHUNK_L; ++r) {
        rho[r].x = fminf(1.f, __expf(t4[r].x - b4[r].x));
        rho[r].y = fminf(1.f, __expf(t4[r].y - b4[r].y));
        rho[r].z = fminf(1.f, __expf(t4[r].z - b4[r].z));
        rho[r].w = fminf(1.f, __expf(t4[r].w - b4[r].w));
        nt_store4(out_rho + base + r * B_DIM, rho[r]);
    }

    // ---- a, b from v/rew ----
    float4 v4[CHUNK_L], r4[CHUNK_L];
    #pragma unroll
    for (int r = 0; r < CHUNK_L; ++r)
        v4[r] = *(const float4*)(v + base + r * B_DIM);
    #pragma unroll
    for (int r = 0; r < CHUNK_L; ++r)
        r4[r] = *(const float4*)(rew + base + r * B_DIM);
    __builtin_amdgcn_sched_barrier(0);

    float4 A  = make_float4(0.f, 0.f, 0.f, 0.f);
    float4 Bc = make_float4(1.f, 1.f, 1.f, 1.f);
    #pragma unroll
    for (int r = CHUNK_L - 1; r >= 0; --r) {
        float4 a4, bv;
        if (last_chunk && r == CHUNK_L - 1) {        // global row T-1
            a4 = v4[r];
            bv = make_float4(0.f, 0.f, 0.f, 0.f);
        } else {
            a4.x = fmaf(rho[r].x, r4[r].x - v4[r].x, v4[r].x);
            a4.y = fmaf(rho[r].y, r4[r].y - v4[r].y, v4[r].y);
            a4.z = fmaf(rho[r].z, r4[r].z - v4[r].z, v4[r].z);
            a4.w = fmaf(rho[r].w, r4[r].w - v4[r].w, v4[r].w);
            bv.x = GAMMA * rho[r].x;
            bv.y = GAMMA * rho[r].y;
            bv.z = GAMMA * rho[r].z;
            bv.w = GAMMA * rho[r].w;
        }
        A.x = fmaf(bv.x, A.x, a4.x);
        A.y = fmaf(bv.y, A.y, a4.y);
        A.z = fmaf(bv.z, A.z, a4.z);
        A.w = fmaf(bv.w, A.w, a4.w);
        Bc.x *= bv.x; Bc.y *= bv.y; Bc.z *= bv.z; Bc.w *= bv.w;
    }

    const int widx = c * B_DIM + col;
    *(float4*)(Aw + widx) = A;        // small, cached (read by carry)
    *(float4*)(Bw + widx) = Bc;
}

// ---------------------------------------------------------------------------
// Pass 2: per-column right-to-left scan of chunk composites -> carries.
// cb[c] = value entering chunk c from the right, i.e. out[(c+1)*L].
// ---------------------------------------------------------------------------
__global__ __launch_bounds__(256) void vtrace_carry(
    const float* __restrict__ Aw, const float* __restrict__ Bw,
    float* __restrict__ cb)
{
    const int j = blockIdx.x * blockDim.x + threadIdx.x;  // 0 .. B-1
    float x = 0.f;
    #pragma unroll 8
    for (int c = NCHUNK - 1; c >= 0; --c) {
        const int i = c * B_DIM + j;
        const float Av = Aw[i];
        const float Bv = Bw[i];
        cb[i] = x;
        x = fmaf(Bv, x, Av);
    }
}

// ---------------------------------------------------------------------------
// Pass 3: RECOMPUTE rho/a from the (L3-resident) inputs -- nothing big we
// wrote is ever re-read -- then sweep the chunk bottom-up and NT-store
// vtrace.  Reads: tlp, blp, v, rew, cb.  Writes: vtrace (NT only).
// ---------------------------------------------------------------------------
__global__ __launch_bounds__(256) void vtrace_apply(
    const float* __restrict__ v, const float* __restrict__ rew,
    const float* __restrict__ tlp, const float* __restrict__ blp,
    float* __restrict__ out_v,           // d_out vtrace slot (final)
    const float* __restrict__ cb)
{
    const int j    = blockIdx.x * blockDim.x + threadIdx.x;  // 0 .. B/4-1
    const int c    = blockIdx.y;
    const int col  = j * 4;
    const int base = c * CHUNK_L * B_DIM + col;
    const bool last_chunk = (c == NCHUNK - 1);

    float4 t4[CHUNK_L], b4[CHUNK_L];
    #pragma unroll
    for (int r = 0; r < CHUNK_L; ++r)
        t4[r] = *(const float4*)(tlp + base + r * B_DIM);
    #pragma unroll
    for (int r = 0; r < CHUNK_L; ++r)
        b4[r] = *(const float4*)(blp + base + r * B_DIM);
    __builtin_amdgcn_sched_barrier(0);

    float4 rho[CHUNK_L];
    #pragma unroll
    for (int r = 0; r < CHUNK_L; ++r) {
        rho[r].x = fminf(1.f, __expf(t4[r].x - b4[r].x));
        rho[r].y = fminf(1.f, __expf(t4[r].y - b4[r].y));
        rho[r].z = fminf(1.f, __expf(t4[r].z - b4[r].z));
        rho[r].w = fminf(1.f, __expf(t4[r].w - b4[r].w));
    }

    float4 v4[CHUNK_L], r4[CHUNK_L];
    #pragma unroll
    for (int r = 0; r < CHUNK_L; ++r)
        v4[r] = *(const float4*)(v + base + r * B_DIM);
    #pragma unroll
    for (int r = 0; r < CHUNK_L; ++r)
        r4[r] = *(const float4*)(rew + base + r * B_DIM);
    __builtin_amdgcn_sched_barrier(0);

    float4 x = *(const float4*)(cb + c * B_DIM + col);  // out[(c+1)*L]

    #pragma unroll
    for (int r = CHUNK_L - 1; r >= 0; --r) {
        float4 a4, bv;
        if (last_chunk && r == CHUNK_L - 1) {        // global row T-1
            a4 = v4[r];
            bv = make_float4(0.f, 0.f, 0.f, 0.f);
        } else {
            a4.x = fmaf(rho[r].x, r4[r].x - v4[r].x, v4[r].x);
            a4.y = fmaf(rho[r].y, r4[r].y - v4[r].y, v4[r].y);
            a4.z = fmaf(rho[r].z, r4[r].z - v4[r].z, v4[r].z);
            a4.w = fmaf(rho[r].w, r4[r].w - v4[r].w, v4[r].w);
            bv.x = GAMMA * rho[r].x;
            bv.y = GAMMA * rho[r].y;
            bv.z = GAMMA * rho[r].z;
            bv.w = GAMMA * rho[r].w;
        }
        x.x = fmaf(bv.x, x.x, a4.x);
        x.y = fmaf(bv.y, x.y, a4.y);
        x.z = fmaf(bv.z, x.z, a4.z);
        x.w = fmaf(bv.w, x.w, a4.w);
        nt_store4(out_v + base + r * B_DIM, x);
    }
}

extern "C" void kernel_launch(void* const* d_in, const int* in_sizes, int n_in,
                              void* d_out, int out_size, void* d_ws, size_t ws_size,
                              hipStream_t stream) {
    const float* v   = (const float*)d_in[0];
    const float* rew = (const float*)d_in[1];
    const float* tlp = (const float*)d_in[2];
    const float* blp = (const float*)d_in[3];

    float* out_v   = (float*)d_out;                          // vtrace slot
    float* out_rho = out_v + (size_t)T_DIM * B_DIM;          // rhos slot

    float* Aw = (float*)d_ws;                                // NCHUNK*B floats
    float* Bw = Aw + (size_t)NCHUNK * B_DIM;                 // NCHUNK*B floats
    float* cb = Bw + (size_t)NCHUNK * B_DIM;                 // NCHUNK*B floats

    dim3 blk(256);
    dim3 grid_scan(B_DIM / 4 / 256, NCHUNK);                 // (8, 256)

    vtrace_pass1<<<grid_scan, blk, 0, stream>>>(v, rew, tlp, blp,
                                                out_rho, Aw, Bw);
    vtrace_carry<<<dim3(B_DIM / 256), blk, 0, stream>>>(Aw, Bw, cb);
    vtrace_apply<<<grid_scan, blk, 0, stream>>>(v, rew, tlp, blp,
                                                out_v, cb);
}

// Round 8
// 128.837 us; speedup vs baseline: 1.0077x; 1.0077x over previous
//
#include <hip/hip_runtime.h>

#define T_DIM 2048
#define B_DIM 8192
#define GAMMA 0.99f
#define NCHUNK 256
#define CHUNK_L 8            // rows per chunk (NCHUNK*CHUNK_L == T_DIM)

typedef float v4f __attribute__((ext_vector_type(4)));

// Inline-asm 16B load: the "=v" output is a live 4-VGPR tuple the compiler
// cannot re-roll or sink -> all issued loads are genuinely outstanding.
__device__ __forceinline__ v4f gload4(const float* p) {
    v4f r;
    asm volatile("global_load_dwordx4 %0, %1, off" : "=v"(r) : "v"(p) : "memory");
    return r;
}
// Inline-asm non-temporal 16B store (no L3 allocation).
__device__ __forceinline__ void ntstore4(float* p, v4f x) {
    asm volatile("global_store_dwordx4 %0, %1, off nt" :: "v"(p), "v"(x) : "memory");
}
__device__ __forceinline__ void nt_store4f(float* p, float4 x) {
    __builtin_nontemporal_store(*(v4f*)&x, (v4f*)p);
}

// ---------------------------------------------------------------------------
// Pass 1 (asm-forced 32-deep MLP): issue ALL 32 global_load_dwordx4
// (8 rows x {tlp,blp,v,rew}) back-to-back, then counted waits:
//   vmcnt(16) -> {tlp,blp} ready -> rho + NT-store rho
//   vmcnt(8)  -> {v,rew} ready (8 NT stores may still be in flight)
//             -> a = v+rho*(rew-v), b = gamma*rho (row T-1: a=v,b=0)
//             -> chunk composite out[c*L] = A + B*out[(c+1)*L]
// Expect VGPR >= 140 (32 live v4f = 128 + rho + addresses).
// ---------------------------------------------------------------------------
__global__ __launch_bounds__(256) void vtrace_pass1(
    const float* __restrict__ v, const float* __restrict__ rew,
    const float* __restrict__ tlp, const float* __restrict__ blp,
    float* __restrict__ out_rho,    // d_out + T*B (final)
    float* __restrict__ Aw, float* __restrict__ Bw)
{
    const int j    = blockIdx.x * blockDim.x + threadIdx.x;  // 0 .. B/4-1
    const int c    = blockIdx.y;
    const int col  = j * 4;
    const int base = c * CHUNK_L * B_DIM + col;
    const bool last_chunk = (c == NCHUNK - 1);

    v4f t4[CHUNK_L], b4[CHUNK_L], v4[CHUNK_L], r4[CHUNK_L];

    // ---- issue phase: 32 loads, nothing else ----
    #pragma unroll
    for (int r = 0; r < CHUNK_L; ++r) t4[r] = gload4(tlp + base + r * B_DIM);
    #pragma unroll
    for (int r = 0; r < CHUNK_L; ++r) b4[r] = gload4(blp + base + r * B_DIM);
    #pragma unroll
    for (int r = 0; r < CHUNK_L; ++r) v4[r] = gload4(v   + base + r * B_DIM);
    #pragma unroll
    for (int r = 0; r < CHUNK_L; ++r) r4[r] = gload4(rew + base + r * B_DIM);

    // ---- wait for the 16 oldest (tlp,blp); 16 still in flight ----
    asm volatile("s_waitcnt vmcnt(16)" ::: "memory");
    __builtin_amdgcn_sched_barrier(0);   // rule #18: pin consumers below wait

    v4f rho[CHUNK_L];
    #pragma unroll
    for (int r = 0; r < CHUNK_L; ++r) {
        rho[r].x = fminf(1.f, __expf(t4[r].x - b4[r].x));
        rho[r].y = fminf(1.f, __expf(t4[r].y - b4[r].y));
        rho[r].z = fminf(1.f, __expf(t4[r].z - b4[r].z));
        rho[r].w = fminf(1.f, __expf(t4[r].w - b4[r].w));
        ntstore4(out_rho + base + r * B_DIM, rho[r]);
    }

    // ---- wait for {v,rew}: 16 loads older than the 8 rho-stores ----
    asm volatile("s_waitcnt vmcnt(8)" ::: "memory");
    __builtin_amdgcn_sched_barrier(0);

    float4 A  = make_float4(0.f, 0.f, 0.f, 0.f);
    float4 Bc = make_float4(1.f, 1.f, 1.f, 1.f);
    #pragma unroll
    for (int r = CHUNK_L - 1; r >= 0; --r) {
        float4 a4, bv;
        if (last_chunk && r == CHUNK_L - 1) {        // global row T-1
            a4 = make_float4(v4[r].x, v4[r].y, v4[r].z, v4[r].w);
            bv = make_float4(0.f, 0.f, 0.f, 0.f);
        } else {
            a4.x = fmaf(rho[r].x, r4[r].x - v4[r].x, v4[r].x);
            a4.y = fmaf(rho[r].y, r4[r].y - v4[r].y, v4[r].y);
            a4.z = fmaf(rho[r].z, r4[r].z - v4[r].z, v4[r].z);
            a4.w = fmaf(rho[r].w, r4[r].w - v4[r].w, v4[r].w);
            bv.x = GAMMA * rho[r].x;
            bv.y = GAMMA * rho[r].y;
            bv.z = GAMMA * rho[r].z;
            bv.w = GAMMA * rho[r].w;
        }
        A.x = fmaf(bv.x, A.x, a4.x);
        A.y = fmaf(bv.y, A.y, a4.y);
        A.z = fmaf(bv.z, A.z, a4.z);
        A.w = fmaf(bv.w, A.w, a4.w);
        Bc.x *= bv.x; Bc.y *= bv.y; Bc.z *= bv.z; Bc.w *= bv.w;
    }

    const int widx = c * B_DIM + col;
    *(float4*)(Aw + widx) = A;        // small, cached (read by carry)
    *(float4*)(Bw + widx) = Bc;
}

// ---------------------------------------------------------------------------
// Pass 2: per-column right-to-left scan of chunk composites -> carries.
// cb[c] = value entering chunk c from the right, i.e. out[(c+1)*L].
// ---------------------------------------------------------------------------
__global__ __launch_bounds__(256) void vtrace_carry(
    const float* __restrict__ Aw, const float* __restrict__ Bw,
    float* __restrict__ cb)
{
    const int j = blockIdx.x * blockDim.x + threadIdx.x;  // 0 .. B-1
    float x = 0.f;
    #pragma unroll 8
    for (int c = NCHUNK - 1; c >= 0; --c) {
        const int i = c * B_DIM + j;
        const float Av = Aw[i];
        const float Bv = Bw[i];
        cb[i] = x;
        x = fmaf(Bv, x, Av);
    }
}

// ---------------------------------------------------------------------------
// Pass 3: RECOMPUTE rho/a from the (now cache-warm) inputs, sweep the chunk
// bottom-up, NT-store vtrace. Unchanged from R7 (ran at ~12-15 TB/s warm).
// ---------------------------------------------------------------------------
__global__ __launch_bounds__(256) void vtrace_apply(
    const float* __restrict__ v, const float* __restrict__ rew,
    const float* __restrict__ tlp, const float* __restrict__ blp,
    float* __restrict__ out_v,           // d_out vtrace slot (final)
    const float* __restrict__ cb)
{
    const int j    = blockIdx.x * blockDim.x + threadIdx.x;  // 0 .. B/4-1
    const int c    = blockIdx.y;
    const int col  = j * 4;
    const int base = c * CHUNK_L * B_DIM + col;
    const bool last_chunk = (c == NCHUNK - 1);

    float4 t4[CHUNK_L], b4[CHUNK_L];
    #pragma unroll
    for (int r = 0; r < CHUNK_L; ++r)
        t4[r] = *(const float4*)(tlp + base + r * B_DIM);
    #pragma unroll
    for (int r = 0; r < CHUNK_L; ++r)
        b4[r] = *(const float4*)(blp + base + r * B_DIM);
    __builtin_amdgcn_sched_barrier(0);

    float4 rho[CHUNK_L];
    #pragma unroll
    for (int r = 0; r < CHUNK_L; ++r) {
        rho[r].x = fminf(1.f, __expf(t4[r].x - b4[r].x));
        rho[r].y = fminf(1.f, __expf(t4[r].y - b4[r].y));
        rho[r].z = fminf(1.f, __expf(t4[r].z - b4[r].z));
        rho[r].w = fminf(1.f, __expf(t4[r].w - b4[r].w));
    }

    float4 v4[CHUNK_L], r4[CHUNK_L];
    #pragma unroll
    for (int r = 0; r < CHUNK_L; ++r)
        v4[r] = *(const float4*)(v + base + r * B_DIM);
    #pragma unroll
    for (int r = 0; r < CHUNK_L; ++r)
        r4[r] = *(const float4*)(rew + base + r * B_DIM);
    __builtin_amdgcn_sched_barrier(0);

    float4 x = *(const float4*)(cb + c * B_DIM + col);  // out[(c+1)*L]

    #pragma unroll
    for (int r = CHUNK_L - 1; r >= 0; --r) {
        float4 a4, bv;
        if (last_chunk && r == CHUNK_L - 1) {        // global row T-1
            a4 = v4[r];
            bv = make_float4(0.f, 0.f, 0.f, 0.f);
        } else {
            a4.x = fmaf(rho[r].x, r4[r].x - v4[r].x, v4[r].x);
            a4.y = fmaf(rho[r].y, r4[r].y - v4[r].y, v4[r].y);
            a4.z = fmaf(rho[r].z, r4[r].z - v4[r].z, v4[r].z);
            a4.w = fmaf(rho[r].w, r4[r].w - v4[r].w, v4[r].w);
            bv.x = GAMMA * rho[r].x;
            bv.y = GAMMA * rho[r].y;
            bv.z = GAMMA * rho[r].z;
            bv.w = GAMMA * rho[r].w;
        }
        x.x = fmaf(bv.x, x.x, a4.x);
        x.y = fmaf(bv.y, x.y, a4.y);
        x.z = fmaf(bv.z, x.z, a4.z);
        x.w = fmaf(bv.w, x.w, a4.w);
        nt_store4f(out_v + base + r * B_DIM, x);
    }
}

extern "C" void kernel_launch(void* const* d_in, const int* in_sizes, int n_in,
                              void* d_out, int out_size, void* d_ws, size_t ws_size,
                              hipStream_t stream) {
    const float* v   = (const float*)d_in[0];
    const float* rew = (const float*)d_in[1];
    const float* tlp = (const float*)d_in[2];
    const float* blp = (const float*)d_in[3];

    float* out_v   = (float*)d_out;                          // vtrace slot
    float* out_rho = out_v + (size_t)T_DIM * B_DIM;          // rhos slot

    float* Aw = (float*)d_ws;                                // NCHUNK*B floats
    float* Bw = Aw + (size_t)NCHUNK * B_DIM;                 // NCHUNK*B floats
    float* cb = Bw + (size_t)NCHUNK * B_DIM;                 // NCHUNK*B floats

    dim3 blk(256);
    dim3 grid_scan(B_DIM / 4 / 256, NCHUNK);                 // (8, 256)

    vtrace_pass1<<<grid_scan, blk, 0, stream>>>(v, rew, tlp, blp,
                                                out_rho, Aw, Bw);
    vtrace_carry<<<dim3(B_DIM / 256), blk, 0, stream>>>(Aw, Bw, cb);
    vtrace_apply<<<grid_scan, blk, 0, stream>>>(v, rew, tlp, blp,
                                                out_v, cb);
}